// Round 1
// baseline (688.211 us; speedup 1.0000x reference)
//
#include <hip/hip_runtime.h>

#define NN 100000
#define NE 3200000
#define NG 1024
#define HD 16

// Padded node count for 16B-aligned buffers
#define NP 100352  // multiple of 256

// ---------------- degree count ----------------
__global__ void count_deg(const int* __restrict__ dst, int* __restrict__ cnt) {
    int e = blockIdx.x * 256 + threadIdx.x;
    if (e < NE) atomicAdd(&cnt[dst[e]], 1);
}

// ---------------- prefix scan (3 kernels) ----------------
__global__ void scan_blocks(const int* __restrict__ cnt, int* __restrict__ excl,
                            int* __restrict__ bsums, int n) {
    __shared__ int tmp[1024];
    int tid = threadIdx.x;
    int i = blockIdx.x * 1024 + tid;
    int v = (i < n) ? cnt[i] : 0;
    tmp[tid] = v;
    __syncthreads();
    for (int off = 1; off < 1024; off <<= 1) {
        int t = (tid >= off) ? tmp[tid - off] : 0;
        __syncthreads();
        tmp[tid] += t;
        __syncthreads();
    }
    if (i < n) excl[i] = tmp[tid] - v;           // exclusive
    if (tid == 1023) bsums[blockIdx.x] = tmp[1023];
}

__global__ void scan_bsums(int* __restrict__ bsums, int nb) {
    __shared__ int tmp[256];
    int tid = threadIdx.x;
    int v = (tid < nb) ? bsums[tid] : 0;
    tmp[tid] = v;
    __syncthreads();
    for (int off = 1; off < 256; off <<= 1) {
        int t = (tid >= off) ? tmp[tid - off] : 0;
        __syncthreads();
        tmp[tid] += t;
        __syncthreads();
    }
    if (tid < nb) bsums[tid] = tmp[tid] - v;     // exclusive
}

__global__ void scan_add(int* __restrict__ excl, const int* __restrict__ bsums,
                         const int* __restrict__ cnt, float* __restrict__ dis, int n) {
    int i = blockIdx.x * 1024 + threadIdx.x;
    if (i < n) {
        excl[i] += bsums[blockIdx.x];
        dis[i] = 1.0f / sqrtf((float)cnt[i] + 1.0f);   // deg includes self loop
    }
}

// ---------------- bucket edges into CSR-by-dst ----------------
__global__ void bucket_edges(const int* __restrict__ src, const int* __restrict__ dst,
                             const int* __restrict__ offs, int* __restrict__ fill,
                             int* __restrict__ srcs) {
    int e = blockIdx.x * 256 + threadIdx.x;
    if (e < NE) {
        int d = dst[e];
        int p = offs[d] + atomicAdd(&fill[d], 1);
        srcs[p] = src[e];
    }
}

// ---------------- embed (one-hot lookup) + transform0 (z[32] @ Wg0) ----------------
__global__ void embed_transform0(const int* __restrict__ types, const int* __restrict__ pos,
                                 const float* __restrict__ W1, const float* __restrict__ b1,
                                 const float* __restrict__ W2, const float* __restrict__ b2,
                                 const float* __restrict__ Wg0, float* __restrict__ h) {
    __shared__ float sW[32 * 16];
    int tid = threadIdx.x;
    sW[tid] = Wg0[tid];
    sW[tid + 256] = Wg0[tid + 256];
    __syncthreads();
    int n = blockIdx.x * 256 + tid;
    if (n >= NN) return;
    int ty = types[n], pp = pos[n];
    float z[32];
#pragma unroll
    for (int j = 0; j < 16; j++) z[j] = W1[ty * 16 + j] + b1[j];
#pragma unroll
    for (int j = 0; j < 16; j++) z[16 + j] = W2[pp * 16 + j] + b2[j];
    float hv[16];
#pragma unroll
    for (int j = 0; j < 16; j++) {
        float a = 0.0f;
#pragma unroll
        for (int k = 0; k < 32; k++) a += z[k] * sW[k * 16 + j];
        hv[j] = a;
    }
    float4* h4 = (float4*)(h + (size_t)n * 16);
#pragma unroll
    for (int q = 0; q < 4; q++)
        h4[q] = make_float4(hv[q * 4 + 0], hv[q * 4 + 1], hv[q * 4 + 2], hv[q * 4 + 3]);
}

// ---------------- generic 16x16 node transform: h = x @ W ----------------
__global__ void transform16(const float* __restrict__ x, const float* __restrict__ W,
                            float* __restrict__ h) {
    __shared__ float sW[256];
    int tid = threadIdx.x;
    sW[tid] = W[tid];
    __syncthreads();
    int n = blockIdx.x * 256 + tid;
    if (n >= NN) return;
    const float4* x4 = (const float4*)(x + (size_t)n * 16);
    float xv[16];
#pragma unroll
    for (int q = 0; q < 4; q++) {
        float4 v = x4[q];
        xv[q * 4 + 0] = v.x; xv[q * 4 + 1] = v.y; xv[q * 4 + 2] = v.z; xv[q * 4 + 3] = v.w;
    }
    float hv[16];
#pragma unroll
    for (int j = 0; j < 16; j++) {
        float a = 0.0f;
#pragma unroll
        for (int k = 0; k < 16; k++) a += xv[k] * sW[k * 16 + j];
        hv[j] = a;
    }
    float4* h4 = (float4*)(h + (size_t)n * 16);
#pragma unroll
    for (int q = 0; q < 4; q++)
        h4[q] = make_float4(hv[q * 4 + 0], hv[q * 4 + 1], hv[q * 4 + 2], hv[q * 4 + 3]);
}

// ---------------- aggregate: 4 threads per node, one float4 of features each ----------------
// out[n] = sum_{e in CSR[n]} h[src]*dis[src]*dis[n] + h[n]*dis[n]^2 + bias, optional ReLU.
// FUSE_POOL: instead of storing, dot with Wo and atomically accumulate per-graph sums.
template <int RELU, int FUSE_POOL>
__global__ void aggregate(const float4* __restrict__ h4, const int* __restrict__ srcs,
                          const int* __restrict__ offs, const int* __restrict__ cnt,
                          const float* __restrict__ dis, const float* __restrict__ bias,
                          float4* __restrict__ out4,
                          const int* __restrict__ batch, const float* __restrict__ Wo,
                          float* __restrict__ pool, int* __restrict__ gcnt) {
    int gid = blockIdx.x * 256 + threadIdx.x;
    int n = gid >> 2;
    int q = gid & 3;
    if (n >= NN) return;
    int beg = offs[n];
    int deg = cnt[n];
    float dn = dis[n];
    float4 acc = make_float4(0.f, 0.f, 0.f, 0.f);
    for (int i = 0; i < deg; i++) {
        int s = srcs[beg + i];
        float c = dis[s] * dn;
        float4 hv = h4[(size_t)s * 4 + q];
        acc.x += hv.x * c; acc.y += hv.y * c; acc.z += hv.z * c; acc.w += hv.w * c;
    }
    float4 hn = h4[(size_t)n * 4 + q];
    float sc = dn * dn;
    acc.x += hn.x * sc + bias[q * 4 + 0];
    acc.y += hn.y * sc + bias[q * 4 + 1];
    acc.z += hn.z * sc + bias[q * 4 + 2];
    acc.w += hn.w * sc + bias[q * 4 + 3];
    if (RELU) {
        acc.x = fmaxf(acc.x, 0.f); acc.y = fmaxf(acc.y, 0.f);
        acc.z = fmaxf(acc.z, 0.f); acc.w = fmaxf(acc.w, 0.f);
    }
    if (!FUSE_POOL) {
        out4[(size_t)n * 4 + q] = acc;
    } else {
        float s = acc.x * Wo[q * 4 + 0] + acc.y * Wo[q * 4 + 1] +
                  acc.z * Wo[q * 4 + 2] + acc.w * Wo[q * 4 + 3];
        s += __shfl_xor(s, 1);
        s += __shfl_xor(s, 2);
        if (q == 0) {
            int g = batch[n];
            atomicAdd(&pool[g], s);
            atomicAdd(&gcnt[g], 1);
        }
    }
}

// ---------------- finalize: mean + bo ----------------
__global__ void finalize(const float* __restrict__ pool, const int* __restrict__ gcnt,
                         const float* __restrict__ bo, float* __restrict__ out) {
    int g = blockIdx.x * 256 + threadIdx.x;
    if (g < NG) {
        float c = fmaxf((float)gcnt[g], 1.0f);
        out[g] = pool[g] / c + bo[0];
    }
}

extern "C" void kernel_launch(void* const* d_in, const int* in_sizes, int n_in,
                              void* d_out, int out_size, void* d_ws, size_t ws_size,
                              hipStream_t stream) {
    const int*   types = (const int*)d_in[0];
    const int*   pos   = (const int*)d_in[1];
    const int*   ei    = (const int*)d_in[2];   // [2, E]: src then dst
    const int*   batch = (const int*)d_in[3];
    const float* W1  = (const float*)d_in[4];
    const float* b1  = (const float*)d_in[5];
    const float* W2  = (const float*)d_in[6];
    const float* b2  = (const float*)d_in[7];
    const float* Wg0 = (const float*)d_in[8];
    const float* bg0 = (const float*)d_in[9];
    const float* Wg1 = (const float*)d_in[10];
    const float* bg1 = (const float*)d_in[11];
    const float* Wg2 = (const float*)d_in[12];
    const float* bg2 = (const float*)d_in[13];
    const float* Wo  = (const float*)d_in[14];
    const float* bo  = (const float*)d_in[15];
    float* out = (float*)d_out;

    const int* esrc = ei;
    const int* edst = ei + NE;

    // ---- workspace layout (4-byte units) ----
    // zero region first: cnt[NP], fill[NP], pool[NG], gcnt[NG]
    int*   cnt   = (int*)d_ws;
    int*   fill  = cnt + NP;
    float* pool  = (float*)(fill + NP);
    int*   gcnt  = (int*)(pool + NG);
    int*   offs  = gcnt + NG;
    int*   bsums = offs + NP;
    float* dis   = (float*)(bsums + 1024);
    int*   srcs  = (int*)(dis + NP);
    float* h     = (float*)(srcs + NE);
    float* xA    = h + (size_t)NP * 16;
    float* xB    = xA + (size_t)NP * 16;
    (void)ws_size; (void)n_in; (void)in_sizes; (void)out_size;

    size_t zero_bytes = (size_t)(2 * NP + 2 * NG) * sizeof(int);
    hipMemsetAsync(d_ws, 0, zero_bytes, stream);

    const int EB = (NE + 255) / 256;
    const int NB1024 = (NN + 1023) / 1024;   // 98
    const int NB256 = (NN + 255) / 256;
    const int QB = (NN * 4 + 255) / 256;

    count_deg<<<EB, 256, 0, stream>>>(edst, cnt);
    scan_blocks<<<NB1024, 1024, 0, stream>>>(cnt, offs, bsums, NN);
    scan_bsums<<<1, 256, 0, stream>>>(bsums, NB1024);
    scan_add<<<NB1024, 1024, 0, stream>>>(offs, bsums, cnt, dis, NN);
    bucket_edges<<<EB, 256, 0, stream>>>(esrc, edst, offs, fill, srcs);

    // layer 0: embed + transform + aggregate + relu
    embed_transform0<<<NB256, 256, 0, stream>>>(types, pos, W1, b1, W2, b2, Wg0, h);
    aggregate<1, 0><<<QB, 256, 0, stream>>>((const float4*)h, srcs, offs, cnt, dis, bg0,
                                            (float4*)xA, batch, Wo, pool, gcnt);
    // layer 1
    transform16<<<NB256, 256, 0, stream>>>(xA, Wg1, h);
    aggregate<1, 0><<<QB, 256, 0, stream>>>((const float4*)h, srcs, offs, cnt, dis, bg1,
                                            (float4*)xB, batch, Wo, pool, gcnt);
    // layer 2 (no relu) fused with pooling dot
    transform16<<<NB256, 256, 0, stream>>>(xB, Wg2, h);
    aggregate<0, 1><<<QB, 256, 0, stream>>>((const float4*)h, srcs, offs, cnt, dis, bg2,
                                            (float4*)xA /*unused*/, batch, Wo, pool, gcnt);

    finalize<<<(NG + 255) / 256, 256, 0, stream>>>(pool, gcnt, bo, out);
}

// Round 2
// 438.235 us; speedup vs baseline: 1.5704x; 1.5704x over previous
//
#include <hip/hip_runtime.h>

#define NN 100000
#define NE 3200000
#define NG 1024
#define HD 16
#define NP 100352            // NN padded to multiple of 256
#define NBUCK 391            // ceil(NN/256) buckets of 256 dst nodes
#define NBLK 256             // blocks for hist/partition
#define CHUNK ((NE + NBLK - 1) / NBLK)   // 12500 edges per block
#define WINCAP 12288         // LDS CSR window (ints); bucket avg 8192, max ~8.6k

// ---- k1: per-bucket edge histogram (LDS-staged) ----
__global__ void hist_buckets(const int* __restrict__ dst, int* __restrict__ bcnt) {
    __shared__ int sm[NBUCK];
    int tid = threadIdx.x;
    for (int i = tid; i < NBUCK; i += 256) sm[i] = 0;
    __syncthreads();
    int s = blockIdx.x * CHUNK, e = min(NE, s + CHUNK);
    for (int i = s + tid; i < e; i += 256) atomicAdd(&sm[dst[i] >> 8], 1);
    __syncthreads();
    for (int i = tid; i < NBUCK; i += 256)
        if (sm[i]) atomicAdd(&bcnt[i], sm[i]);
}

// ---- k2: exclusive scan of 391 bucket counts (1 block) ----
__global__ void scan_buckets(const int* __restrict__ bcnt, int* __restrict__ bbase) {
    __shared__ int tmp[512];
    int tid = threadIdx.x;
    int v = (tid < NBUCK) ? bcnt[tid] : 0;
    tmp[tid] = v;
    __syncthreads();
    for (int off = 1; off < 512; off <<= 1) {
        int t = (tid >= off) ? tmp[tid - off] : 0;
        __syncthreads();
        tmp[tid] += t;
        __syncthreads();
    }
    if (tid < NBUCK) bbase[tid] = tmp[tid] - v;
}

// ---- k3: partition edges into bucket regions, packed (dst&255)<<17 | src ----
__global__ void partition(const int* __restrict__ src, const int* __restrict__ dst,
                          const int* __restrict__ bbase, int* __restrict__ bfill,
                          int* __restrict__ part) {
    __shared__ int smh[NBUCK];
    __shared__ int smc[NBUCK];
    int tid = threadIdx.x;
    for (int i = tid; i < NBUCK; i += 256) smh[i] = 0;
    __syncthreads();
    int s = blockIdx.x * CHUNK, e = min(NE, s + CHUNK);
    for (int i = s + tid; i < e; i += 256) atomicAdd(&smh[dst[i] >> 8], 1);
    __syncthreads();
    for (int i = tid; i < NBUCK; i += 256) {
        int c = smh[i];
        smc[i] = c ? (bbase[i] + atomicAdd(&bfill[i], c)) : 0;
    }
    __syncthreads();
    for (int i = s + tid; i < e; i += 256) {
        int d = dst[i];
        int b = d >> 8;
        int p = atomicAdd(&smc[b], 1);
        part[p] = src[i] | ((d & 255) << 17);
    }
}

// ---- k4: per-bucket CSR build in LDS; sequential write-out ----
__global__ void build_csr(const int* __restrict__ part, const int* __restrict__ bbase,
                          const int* __restrict__ bcnt, int* __restrict__ cnt,
                          int* __restrict__ offs, float* __restrict__ dis,
                          int* __restrict__ srcs) {
    __shared__ int sm_cnt[256];
    __shared__ int sm_off[256];
    __shared__ int sm_cur[256];
    __shared__ int sm_win[WINCAP];
    int b = blockIdx.x, tid = threadIdx.x;
    int base = bbase[b], m = bcnt[b];
    sm_cnt[tid] = 0;
    __syncthreads();
    for (int i = tid; i < m; i += 256) atomicAdd(&sm_cnt[part[base + i] >> 17], 1);
    __syncthreads();
    int v = sm_cnt[tid];
    sm_off[tid] = v;
    __syncthreads();
    for (int off = 1; off < 256; off <<= 1) {
        int t = (tid >= off) ? sm_off[tid - off] : 0;
        __syncthreads();
        sm_off[tid] += t;
        __syncthreads();
    }
    int excl = sm_off[tid] - v;
    int n = b * 256 + tid;
    if (n < NN) {
        cnt[n] = v;
        offs[n] = base + excl;
        dis[n] = rsqrtf((float)v + 1.0f);
    }
    sm_cur[tid] = excl;
    __syncthreads();
    if (m <= WINCAP) {
        for (int i = tid; i < m; i += 256) {
            int p = part[base + i];
            int l = atomicAdd(&sm_cur[p >> 17], 1);
            sm_win[l] = p & 0x1FFFF;
        }
        __syncthreads();
        for (int i = tid; i < m; i += 256) srcs[base + i] = sm_win[i];
    } else {  // safety fallback, not expected for this input
        for (int i = tid; i < m; i += 256) {
            int p = part[base + i];
            int l = atomicAdd(&sm_cur[p >> 17], 1);
            srcs[base + l] = p & 0x1FFFF;
        }
    }
}

// ---- embed (one-hot lookup) + transform0 (z[32] @ Wg0) ----
__global__ void embed_transform0(const int* __restrict__ types, const int* __restrict__ pos,
                                 const float* __restrict__ W1, const float* __restrict__ b1,
                                 const float* __restrict__ W2, const float* __restrict__ b2,
                                 const float* __restrict__ Wg0, float* __restrict__ h) {
    __shared__ float sW[32 * 16];
    int tid = threadIdx.x;
    sW[tid] = Wg0[tid];
    sW[tid + 256] = Wg0[tid + 256];
    __syncthreads();
    int n = blockIdx.x * 256 + tid;
    if (n >= NN) return;
    int ty = types[n], pp = pos[n];
    float z[32];
#pragma unroll
    for (int j = 0; j < 16; j++) z[j] = W1[ty * 16 + j] + b1[j];
#pragma unroll
    for (int j = 0; j < 16; j++) z[16 + j] = W2[pp * 16 + j] + b2[j];
    float hv[16];
#pragma unroll
    for (int j = 0; j < 16; j++) {
        float a = 0.0f;
#pragma unroll
        for (int k = 0; k < 32; k++) a += z[k] * sW[k * 16 + j];
        hv[j] = a;
    }
    float4* h4 = (float4*)(h + (size_t)n * 16);
#pragma unroll
    for (int q = 0; q < 4; q++)
        h4[q] = make_float4(hv[q * 4 + 0], hv[q * 4 + 1], hv[q * 4 + 2], hv[q * 4 + 3]);
}

// ---- generic 16x16 node transform: h = x @ W ----
__global__ void transform16(const float* __restrict__ x, const float* __restrict__ W,
                            float* __restrict__ h) {
    __shared__ float sW[256];
    int tid = threadIdx.x;
    sW[tid] = W[tid];
    __syncthreads();
    int n = blockIdx.x * 256 + tid;
    if (n >= NN) return;
    const float4* x4 = (const float4*)(x + (size_t)n * 16);
    float xv[16];
#pragma unroll
    for (int q = 0; q < 4; q++) {
        float4 v = x4[q];
        xv[q * 4 + 0] = v.x; xv[q * 4 + 1] = v.y; xv[q * 4 + 2] = v.z; xv[q * 4 + 3] = v.w;
    }
    float hv[16];
#pragma unroll
    for (int j = 0; j < 16; j++) {
        float a = 0.0f;
#pragma unroll
        for (int k = 0; k < 16; k++) a += xv[k] * sW[k * 16 + j];
        hv[j] = a;
    }
    float4* h4 = (float4*)(h + (size_t)n * 16);
#pragma unroll
    for (int q = 0; q < 4; q++)
        h4[q] = make_float4(hv[q * 4 + 0], hv[q * 4 + 1], hv[q * 4 + 2], hv[q * 4 + 3]);
}

// ---- aggregate: 4 threads/node, float4 of features each ----
template <int RELU, int FUSE_POOL>
__global__ void aggregate(const float4* __restrict__ h4, const int* __restrict__ srcs,
                          const int* __restrict__ offs, const int* __restrict__ cnt,
                          const float* __restrict__ dis, const float* __restrict__ bias,
                          float4* __restrict__ out4,
                          const int* __restrict__ batch, const float* __restrict__ Wo,
                          float* __restrict__ pool, int* __restrict__ gcnt) {
    int gid = blockIdx.x * 256 + threadIdx.x;
    int n = gid >> 2;
    int q = gid & 3;
    if (n >= NN) return;
    int beg = offs[n];
    int deg = cnt[n];
    float dn = dis[n];
    float4 acc = make_float4(0.f, 0.f, 0.f, 0.f);
    for (int i = 0; i < deg; i++) {
        int s = srcs[beg + i];
        float c = dis[s] * dn;
        float4 hv = h4[(size_t)s * 4 + q];
        acc.x += hv.x * c; acc.y += hv.y * c; acc.z += hv.z * c; acc.w += hv.w * c;
    }
    float4 hn = h4[(size_t)n * 4 + q];
    float sc = dn * dn;
    acc.x += hn.x * sc + bias[q * 4 + 0];
    acc.y += hn.y * sc + bias[q * 4 + 1];
    acc.z += hn.z * sc + bias[q * 4 + 2];
    acc.w += hn.w * sc + bias[q * 4 + 3];
    if (RELU) {
        acc.x = fmaxf(acc.x, 0.f); acc.y = fmaxf(acc.y, 0.f);
        acc.z = fmaxf(acc.z, 0.f); acc.w = fmaxf(acc.w, 0.f);
    }
    if (!FUSE_POOL) {
        out4[(size_t)n * 4 + q] = acc;
    } else {
        float s = acc.x * Wo[q * 4 + 0] + acc.y * Wo[q * 4 + 1] +
                  acc.z * Wo[q * 4 + 2] + acc.w * Wo[q * 4 + 3];
        s += __shfl_xor(s, 1);
        s += __shfl_xor(s, 2);
        if (q == 0) {
            int g = batch[n];
            atomicAdd(&pool[g], s);
            atomicAdd(&gcnt[g], 1);
        }
    }
}

__global__ void finalize(const float* __restrict__ pool, const int* __restrict__ gcnt,
                         const float* __restrict__ bo, float* __restrict__ out) {
    int g = blockIdx.x * 256 + threadIdx.x;
    if (g < NG) {
        float c = fmaxf((float)gcnt[g], 1.0f);
        out[g] = pool[g] / c + bo[0];
    }
}

extern "C" void kernel_launch(void* const* d_in, const int* in_sizes, int n_in,
                              void* d_out, int out_size, void* d_ws, size_t ws_size,
                              hipStream_t stream) {
    const int*   types = (const int*)d_in[0];
    const int*   pos   = (const int*)d_in[1];
    const int*   ei    = (const int*)d_in[2];   // [2, E]: src then dst
    const int*   batch = (const int*)d_in[3];
    const float* W1  = (const float*)d_in[4];
    const float* b1  = (const float*)d_in[5];
    const float* W2  = (const float*)d_in[6];
    const float* b2  = (const float*)d_in[7];
    const float* Wg0 = (const float*)d_in[8];
    const float* bg0 = (const float*)d_in[9];
    const float* Wg1 = (const float*)d_in[10];
    const float* bg1 = (const float*)d_in[11];
    const float* Wg2 = (const float*)d_in[12];
    const float* bg2 = (const float*)d_in[13];
    const float* Wo  = (const float*)d_in[14];
    const float* bo  = (const float*)d_in[15];
    float* out = (float*)d_out;

    const int* esrc = ei;
    const int* edst = ei + NE;

    // ---- workspace layout (ints) ----
    // zero region: bcnt[512], bfill[512], pool[1024], gcnt[1024]  (12 KB)
    int*   bcnt  = (int*)d_ws;
    int*   bfill = bcnt + 512;
    float* pool  = (float*)(bfill + 512);
    int*   gcnt  = (int*)(pool + NG);
    int*   bbase = gcnt + NG;                    // 512
    int*   cnt   = bbase + 512;                  // NP
    int*   offs  = cnt + NP;                     // NP
    float* dis   = (float*)(offs + NP);          // NP
    int*   srcs  = (int*)(dis + NP);             // NE
    int*   part  = srcs + NE;                    // NE  (bufA aliases this)
    float* bufA  = (float*)part;                 // NP*16 floats <= NE ints
    float* bufB  = (float*)(part + NE);          // NP*16 floats
    (void)ws_size; (void)n_in; (void)in_sizes; (void)out_size;

    hipMemsetAsync(d_ws, 0, (size_t)(1024 + 2 * NG) * sizeof(int), stream);

    const int NB256 = (NN + 255) / 256;          // 391
    const int QB = (NN * 4 + 255) / 256;

    hist_buckets<<<NBLK, 256, 0, stream>>>(edst, bcnt);
    scan_buckets<<<1, 512, 0, stream>>>(bcnt, bbase);
    partition<<<NBLK, 256, 0, stream>>>(esrc, edst, bbase, bfill, part);
    build_csr<<<NBUCK, 256, 0, stream>>>(part, bbase, bcnt, cnt, offs, dis, srcs);

    // layer 0
    embed_transform0<<<NB256, 256, 0, stream>>>(types, pos, W1, b1, W2, b2, Wg0, bufA);
    aggregate<1, 0><<<QB, 256, 0, stream>>>((const float4*)bufA, srcs, offs, cnt, dis, bg0,
                                            (float4*)bufB, batch, Wo, pool, gcnt);
    // layer 1
    transform16<<<NB256, 256, 0, stream>>>(bufB, Wg1, bufA);
    aggregate<1, 0><<<QB, 256, 0, stream>>>((const float4*)bufA, srcs, offs, cnt, dis, bg1,
                                            (float4*)bufB, batch, Wo, pool, gcnt);
    // layer 2 (no relu) fused with pooling dot
    transform16<<<NB256, 256, 0, stream>>>(bufB, Wg2, bufA);
    aggregate<0, 1><<<QB, 256, 0, stream>>>((const float4*)bufA, srcs, offs, cnt, dis, bg2,
                                            (float4*)bufB /*unused*/, batch, Wo, pool, gcnt);

    finalize<<<(NG + 255) / 256, 256, 0, stream>>>(pool, gcnt, bo, out);
}

// Round 3
// 335.832 us; speedup vs baseline: 2.0493x; 1.3049x over previous
//
#include <hip/hip_runtime.h>
#include <hip/hip_fp16.h>

#define NN 100000
#define NE 3200000
#define NG 1024
#define NP 100352            // NN padded to multiple of 256
#define NBUCK 391            // ceil(NN/256) buckets of 256 dst nodes
#define NBLK 256
#define CHUNK ((NE + NBLK - 1) / NBLK)
#define WINCAP 12288

// ---------- fp16 pack/unpack helpers ----------
static __device__ inline void acc_u2(float4& acc, uint2 u) {
    __half2* ph = reinterpret_cast<__half2*>(&u);
    float2 lo = __half22float2(ph[0]);
    float2 hi = __half22float2(ph[1]);
    acc.x += lo.x; acc.y += lo.y; acc.z += hi.x; acc.w += hi.y;
}
static __device__ inline uint2 pack4(float a, float b, float c, float d) {
    __half2 lo = __floats2half2_rn(a, b);
    __half2 hi = __floats2half2_rn(c, d);
    uint2 u;
    u.x = *reinterpret_cast<unsigned int*>(&lo);
    u.y = *reinterpret_cast<unsigned int*>(&hi);
    return u;
}
static __device__ inline float4 shfl_xor4(float4 v, int m) {
    float4 r;
    r.x = __shfl_xor(v.x, m); r.y = __shfl_xor(v.y, m);
    r.z = __shfl_xor(v.z, m); r.w = __shfl_xor(v.w, m);
    return r;
}

// ---- k1: per-bucket edge histogram ----
__global__ void hist_buckets(const int* __restrict__ dst, int* __restrict__ bcnt) {
    __shared__ int sm[NBUCK];
    int tid = threadIdx.x;
    for (int i = tid; i < NBUCK; i += 256) sm[i] = 0;
    __syncthreads();
    int s = blockIdx.x * CHUNK, e = min(NE, s + CHUNK);
    for (int i = s + tid; i < e; i += 256) atomicAdd(&sm[dst[i] >> 8], 1);
    __syncthreads();
    for (int i = tid; i < NBUCK; i += 256)
        if (sm[i]) atomicAdd(&bcnt[i], sm[i]);
}

// ---- k2: exclusive scan of bucket counts ----
__global__ void scan_buckets(const int* __restrict__ bcnt, int* __restrict__ bbase) {
    __shared__ int tmp[512];
    int tid = threadIdx.x;
    int v = (tid < NBUCK) ? bcnt[tid] : 0;
    tmp[tid] = v;
    __syncthreads();
    for (int off = 1; off < 512; off <<= 1) {
        int t = (tid >= off) ? tmp[tid - off] : 0;
        __syncthreads();
        tmp[tid] += t;
        __syncthreads();
    }
    if (tid < NBUCK) bbase[tid] = tmp[tid] - v;
}

// ---- k3: partition edges into bucket regions, packed (dst&255)<<17 | src ----
__global__ void partition(const int* __restrict__ src, const int* __restrict__ dst,
                          const int* __restrict__ bbase, int* __restrict__ bfill,
                          int* __restrict__ part) {
    __shared__ int smh[NBUCK];
    __shared__ int smc[NBUCK];
    int tid = threadIdx.x;
    for (int i = tid; i < NBUCK; i += 256) smh[i] = 0;
    __syncthreads();
    int s = blockIdx.x * CHUNK, e = min(NE, s + CHUNK);
    for (int i = s + tid; i < e; i += 256) atomicAdd(&smh[dst[i] >> 8], 1);
    __syncthreads();
    for (int i = tid; i < NBUCK; i += 256) {
        int c = smh[i];
        smc[i] = c ? (bbase[i] + atomicAdd(&bfill[i], c)) : 0;
    }
    __syncthreads();
    for (int i = s + tid; i < e; i += 256) {
        int d = dst[i];
        int b = d >> 8;
        int p = atomicAdd(&smc[b], 1);
        part[p] = src[i] | ((d & 255) << 17);
    }
}

// ---- k4: per-bucket CSR build in LDS; sequential write-out; also computes dis ----
__global__ void build_csr(const int* __restrict__ part, const int* __restrict__ bbase,
                          const int* __restrict__ bcnt, int* __restrict__ cnt,
                          int* __restrict__ offs, float* __restrict__ dis,
                          int* __restrict__ srcs) {
    __shared__ int sm_cnt[256];
    __shared__ int sm_off[256];
    __shared__ int sm_cur[256];
    __shared__ int sm_win[WINCAP];
    int b = blockIdx.x, tid = threadIdx.x;
    int base = bbase[b], m = bcnt[b];
    sm_cnt[tid] = 0;
    __syncthreads();
    for (int i = tid; i < m; i += 256) atomicAdd(&sm_cnt[part[base + i] >> 17], 1);
    __syncthreads();
    int v = sm_cnt[tid];
    sm_off[tid] = v;
    __syncthreads();
    for (int off = 1; off < 256; off <<= 1) {
        int t = (tid >= off) ? sm_off[tid - off] : 0;
        __syncthreads();
        sm_off[tid] += t;
        __syncthreads();
    }
    int excl = sm_off[tid] - v;
    int n = b * 256 + tid;
    if (n < NN) {
        cnt[n] = v;
        offs[n] = base + excl;
        dis[n] = rsqrtf((float)v + 1.0f);
    }
    sm_cur[tid] = excl;
    __syncthreads();
    if (m <= WINCAP) {
        for (int i = tid; i < m; i += 256) {
            int p = part[base + i];
            int l = atomicAdd(&sm_cur[p >> 17], 1);
            sm_win[l] = p & 0x1FFFF;
        }
        __syncthreads();
        for (int i = tid; i < m; i += 256) srcs[base + i] = sm_win[i];
    } else {
        for (int i = tid; i < m; i += 256) {
            int p = part[base + i];
            int l = atomicAdd(&sm_cur[p >> 17], 1);
            srcs[base + l] = p & 0x1FFFF;
        }
    }
}

// ---- embed one-hot + transform by Wg0, premultiply dis, fp16 out ----
__global__ void embed_tf0(const int* __restrict__ types, const int* __restrict__ pos,
                          const float* __restrict__ W1, const float* __restrict__ b1,
                          const float* __restrict__ W2, const float* __restrict__ b2,
                          const float* __restrict__ Wg0, const float* __restrict__ dis,
                          uint2* __restrict__ hs) {
    __shared__ float sW[32 * 16];
    int tid = threadIdx.x;
    sW[tid] = Wg0[tid];
    sW[tid + 256] = Wg0[tid + 256];
    __syncthreads();
    int n = blockIdx.x * 256 + tid;
    if (n >= NN) return;
    int ty = types[n], pp = pos[n];
    float z[32];
#pragma unroll
    for (int j = 0; j < 16; j++) z[j] = W1[ty * 16 + j] + b1[j];
#pragma unroll
    for (int j = 0; j < 16; j++) z[16 + j] = W2[pp * 16 + j] + b2[j];
    float dn = dis[n];
    uint2 o[4];
#pragma unroll
    for (int q = 0; q < 4; q++) {
        float hv[4];
#pragma unroll
        for (int m = 0; m < 4; m++) {
            float a = 0.0f;
#pragma unroll
            for (int k = 0; k < 32; k++) a += z[k] * sW[k * 16 + q * 4 + m];
            hv[m] = a * dn;
        }
        o[q] = pack4(hv[0], hv[1], hv[2], hv[3]);
    }
#pragma unroll
    for (int q = 0; q < 4; q++) hs[(size_t)n * 4 + q] = o[q];
}

// ---- fused aggregate + (transform | pool): 4 threads per node ----
// z[n] = dn*(sum_{e} hs[src] + hs[n]) + bias ; optional relu
// !FUSE_POOL: hs_out[n] = (z @ Wn) * dn   (fp16)
//  FUSE_POOL: pool[batch[n]] += z . Wn(=Wo); gcnt[batch[n]] += 1
template <int RELU, int FUSE_POOL>
__global__ void agg_tf(const uint2* __restrict__ hs, const int* __restrict__ srcs,
                       const int* __restrict__ offs, const int* __restrict__ cnt,
                       const float* __restrict__ dis, const float* __restrict__ bias,
                       const float* __restrict__ Wn, uint2* __restrict__ hs_out,
                       const int* __restrict__ batch,
                       float* __restrict__ pool, int* __restrict__ gcnt) {
    __shared__ float sW[256];
    int tid = threadIdx.x;
    if (!FUSE_POOL) {
        sW[tid] = Wn[tid];
        __syncthreads();
    }
    int gid = blockIdx.x * 256 + tid;
    int n = gid >> 2, q = gid & 3;
    if (n >= NN) return;
    int beg = offs[n], deg = cnt[n];
    float dn = dis[n];
    float4 acc = make_float4(0.f, 0.f, 0.f, 0.f);
    int i = 0;
    for (; i + 4 <= deg; i += 4) {
        int s0 = srcs[beg + i + 0];
        int s1 = srcs[beg + i + 1];
        int s2 = srcs[beg + i + 2];
        int s3 = srcs[beg + i + 3];
        uint2 a0 = hs[(size_t)s0 * 4 + q];
        uint2 a1 = hs[(size_t)s1 * 4 + q];
        uint2 a2 = hs[(size_t)s2 * 4 + q];
        uint2 a3 = hs[(size_t)s3 * 4 + q];
        acc_u2(acc, a0); acc_u2(acc, a1); acc_u2(acc, a2); acc_u2(acc, a3);
    }
    for (; i < deg; i++) {
        int s = srcs[beg + i];
        acc_u2(acc, hs[(size_t)s * 4 + q]);
    }
    acc_u2(acc, hs[(size_t)n * 4 + q]);   // self loop (hs = h*dis, self coef dn*dn)
    float4 b4 = ((const float4*)bias)[q];
    acc.x = fmaf(acc.x, dn, b4.x);
    acc.y = fmaf(acc.y, dn, b4.y);
    acc.z = fmaf(acc.z, dn, b4.z);
    acc.w = fmaf(acc.w, dn, b4.w);
    if (RELU) {
        acc.x = fmaxf(acc.x, 0.f); acc.y = fmaxf(acc.y, 0.f);
        acc.z = fmaxf(acc.z, 0.f); acc.w = fmaxf(acc.w, 0.f);
    }
    if (FUSE_POOL) {
        float4 w4 = ((const float4*)Wn)[q];
        float s = acc.x * w4.x + acc.y * w4.y + acc.z * w4.z + acc.w * w4.w;
        s += __shfl_xor(s, 1);
        s += __shfl_xor(s, 2);
        if (q == 0) {
            int g = batch[n];
            atomicAdd(&pool[g], s);
            atomicAdd(&gcnt[g], 1);
        }
    } else {
        // exchange quad features, compute z @ Wn for this thread's 4 outputs
        float4 vals[4];
        vals[0] = acc;
        vals[1] = shfl_xor4(acc, 1);
        vals[2] = shfl_xor4(acc, 2);
        vals[3] = shfl_xor4(acc, 3);
        const float4* sW4 = (const float4*)sW;
        float4 hv = make_float4(0.f, 0.f, 0.f, 0.f);
#pragma unroll
        for (int m = 0; m < 4; m++) {
            float4 v = vals[m];
            int rb = (q ^ m) << 2;
            float4 w;
            w = sW4[(rb + 0) * 4 + q];
            hv.x += v.x * w.x; hv.y += v.x * w.y; hv.z += v.x * w.z; hv.w += v.x * w.w;
            w = sW4[(rb + 1) * 4 + q];
            hv.x += v.y * w.x; hv.y += v.y * w.y; hv.z += v.y * w.z; hv.w += v.y * w.w;
            w = sW4[(rb + 2) * 4 + q];
            hv.x += v.z * w.x; hv.y += v.z * w.y; hv.z += v.z * w.z; hv.w += v.z * w.w;
            w = sW4[(rb + 3) * 4 + q];
            hv.x += v.w * w.x; hv.y += v.w * w.y; hv.z += v.w * w.z; hv.w += v.w * w.w;
        }
        hs_out[(size_t)n * 4 + q] = pack4(hv.x * dn, hv.y * dn, hv.z * dn, hv.w * dn);
    }
}

__global__ void finalize(const float* __restrict__ pool, const int* __restrict__ gcnt,
                         const float* __restrict__ bo, float* __restrict__ out) {
    int g = blockIdx.x * 256 + threadIdx.x;
    if (g < NG) {
        float c = fmaxf((float)gcnt[g], 1.0f);
        out[g] = pool[g] / c + bo[0];
    }
}

extern "C" void kernel_launch(void* const* d_in, const int* in_sizes, int n_in,
                              void* d_out, int out_size, void* d_ws, size_t ws_size,
                              hipStream_t stream) {
    const int*   types = (const int*)d_in[0];
    const int*   pos   = (const int*)d_in[1];
    const int*   ei    = (const int*)d_in[2];   // [2, E]: src then dst
    const int*   batch = (const int*)d_in[3];
    const float* W1  = (const float*)d_in[4];
    const float* b1  = (const float*)d_in[5];
    const float* W2  = (const float*)d_in[6];
    const float* b2  = (const float*)d_in[7];
    const float* Wg0 = (const float*)d_in[8];
    const float* bg0 = (const float*)d_in[9];
    const float* Wg1 = (const float*)d_in[10];
    const float* bg1 = (const float*)d_in[11];
    const float* Wg2 = (const float*)d_in[12];
    const float* bg2 = (const float*)d_in[13];
    const float* Wo  = (const float*)d_in[14];
    const float* bo  = (const float*)d_in[15];
    float* out = (float*)d_out;

    const int* esrc = ei;
    const int* edst = ei + NE;

    // ---- workspace layout (ints) ----
    int*   bcnt  = (int*)d_ws;                   // 512  (zeroed)
    int*   bfill = bcnt + 512;                   // 512  (zeroed)
    float* pool  = (float*)(bfill + 512);        // 1024 (zeroed)
    int*   gcnt  = (int*)(pool + NG);            // 1024 (zeroed)
    int*   bbase = gcnt + NG;                    // 512
    int*   cnt   = bbase + 512;                  // NP
    int*   offs  = cnt + NP;                     // NP
    float* dis   = (float*)(offs + NP);          // NP
    int*   srcs  = (int*)(dis + NP);             // NE
    int*   part  = srcs + NE;                    // NE  (hs buffers alias this)
    uint2* hsA   = (uint2*)part;                 // NP*4 uint2 = 3.2 MB
    uint2* hsB   = (uint2*)(part + NE / 2);      // 3.2 MB (part is 12.8 MB)
    (void)ws_size; (void)n_in; (void)in_sizes; (void)out_size;

    hipMemsetAsync(d_ws, 0, (size_t)(1024 + 2 * NG) * sizeof(int), stream);

    const int NB256 = (NN + 255) / 256;          // 391
    const int QB = (NN * 4 + 255) / 256;         // 1563

    hist_buckets<<<NBLK, 256, 0, stream>>>(edst, bcnt);
    scan_buckets<<<1, 512, 0, stream>>>(bcnt, bbase);
    partition<<<NBLK, 256, 0, stream>>>(esrc, edst, bbase, bfill, part);
    build_csr<<<NBUCK, 256, 0, stream>>>(part, bbase, bcnt, cnt, offs, dis, srcs);

    // layer 0 input: hs0 = (z0 @ Wg0) * dis  (fp16)
    embed_tf0<<<NB256, 256, 0, stream>>>(types, pos, W1, b1, W2, b2, Wg0, dis, hsA);
    // layer 0 agg + relu + transform Wg1 -> hs1
    agg_tf<1, 0><<<QB, 256, 0, stream>>>(hsA, srcs, offs, cnt, dis, bg0, Wg1, hsB,
                                         batch, pool, gcnt);
    // layer 1 agg + relu + transform Wg2 -> hs2
    agg_tf<1, 0><<<QB, 256, 0, stream>>>(hsB, srcs, offs, cnt, dis, bg1, Wg2, hsA,
                                         batch, pool, gcnt);
    // layer 2 agg (no relu) + Wo dot + pool
    agg_tf<0, 1><<<QB, 256, 0, stream>>>(hsA, srcs, offs, cnt, dis, bg2, Wo, hsB /*unused*/,
                                         batch, pool, gcnt);

    finalize<<<(NG + 255) / 256, 256, 0, stream>>>(pool, gcnt, bo, out);
}